// Round 1
// baseline (1621.840 us; speedup 1.0000x reference)
//
#include <hip/hip_runtime.h>
#include <math.h>

// Problem constants (from reference): S=512, B=256, V=100000, E=128, H=256
#define S_LEN 512
#define B_SZ  256
#define E_SZ  128
#define H_SZ  256

#define ROWS_PER_BLOCK 128   // rows of xproj per block in the projection GEMM

// ---------------------------------------------------------------------------
// Kernel 1: fused embedding gather + input projection
//   xproj[row, h] = sum_e emb[X[row], e] * W_ih[h, e] + b_ih[h] + b_hh[h]
//   row = s*B + b, 131072 rows total.
// Thread h (0..255) owns output column h; W_ih row h lives in 128 VGPRs.
// The emb row address is wave-uniform (same row for whole block) -> scalar
// loads; FMA uses 4 accumulators to break the dependent chain.
// ---------------------------------------------------------------------------
__global__ __launch_bounds__(256, 2) void embed_proj_kernel(
    const int*   __restrict__ X,
    const float* __restrict__ emb,
    const float* __restrict__ W_ih,
    const float* __restrict__ b_ih,
    const float* __restrict__ b_hh,
    float*       __restrict__ xproj)
{
    const int h    = threadIdx.x;
    const int row0 = blockIdx.x * ROWS_PER_BLOCK;

    // Load this thread's W_ih row into registers (one-time, L2/L3 cached).
    float w[E_SZ];
    const float4* wr = (const float4*)(W_ih + (size_t)h * E_SZ);
#pragma unroll
    for (int j = 0; j < E_SZ / 4; ++j) {
        float4 t = wr[j];
        w[4*j+0] = t.x; w[4*j+1] = t.y; w[4*j+2] = t.z; w[4*j+3] = t.w;
    }
    const float bias = b_ih[h] + b_hh[h];

    for (int r = 0; r < ROWS_PER_BLOCK; ++r) {
        const int row = row0 + r;
        const int tok = X[row];                       // uniform across block
        const float4* a = (const float4*)(emb + (size_t)tok * E_SZ);
        float acc0 = bias, acc1 = 0.f, acc2 = 0.f, acc3 = 0.f;
#pragma unroll
        for (int j = 0; j < E_SZ / 4; ++j) {
            float4 av = a[j];                         // uniform -> s_load path
            acc0 += av.x * w[4*j+0];
            acc1 += av.y * w[4*j+1];
            acc2 += av.z * w[4*j+2];
            acc3 += av.w * w[4*j+3];
        }
        xproj[(size_t)row * H_SZ + h] = (acc0 + acc1) + (acc2 + acc3);  // coalesced
    }
}

// ---------------------------------------------------------------------------
// Kernel 2: recurrent scan + log_softmax epilogue.
// One block per batch element b (256 blocks -> 1 per CU). 1024 threads:
//   tg = tid>>8 (k-quarter), h = tid&255 (output index).
// Thread holds W_hh[h, 64*tg .. 64*tg+63] in 64 VGPRs.
// Per step: 64 FMAs vs broadcast LDS h-state, 4-way LDS reduce, tanh (tg0),
// with the next step's xproj row prefetched during compute.
// ---------------------------------------------------------------------------
__global__ __launch_bounds__(1024, 4) void rnn_scan_kernel(
    const float* __restrict__ xproj,
    const float* __restrict__ W_hh,
    float*       __restrict__ out)
{
    const int b   = blockIdx.x;
    const int tid = threadIdx.x;
    const int tg  = tid >> 8;
    const int h   = tid & 255;
    const int k0  = tg * 64;

    __shared__ __align__(16) float hstate[H_SZ];
    __shared__ __align__(16) float red[1024];

    // W_hh chunk into registers.
    float w[64];
    const float4* wr = (const float4*)(W_hh + (size_t)h * H_SZ + k0);
#pragma unroll
    for (int j = 0; j < 16; ++j) {
        float4 t = wr[j];
        w[4*j+0] = t.x; w[4*j+1] = t.y; w[4*j+2] = t.z; w[4*j+3] = t.w;
    }

    if (tid < H_SZ) hstate[tid] = 0.f;
    float xp_cur = (tg == 0) ? xproj[(size_t)(0 * B_SZ + b) * H_SZ + h] : 0.f;
    __syncthreads();

    for (int s = 0; s < S_LEN; ++s) {
        // Prefetch next step's xproj row (hides HBM latency behind compute).
        float xp_next = 0.f;
        if (tg == 0 && s + 1 < S_LEN)
            xp_next = xproj[(size_t)((s + 1) * B_SZ + b) * H_SZ + h];

        // partial_tg[h] = sum_{k in quarter} W_hh[h,k] * hstate[k]
        const float4* hs4 = (const float4*)(hstate + k0);
        float p0 = 0.f, p1 = 0.f, p2 = 0.f, p3 = 0.f;
#pragma unroll
        for (int j = 0; j < 16; ++j) {
            float4 hv = hs4[j];                    // broadcast read, no conflicts
            p0 += w[4*j+0] * hv.x;
            p1 += w[4*j+1] * hv.y;
            p2 += w[4*j+2] * hv.z;
            p3 += w[4*j+3] * hv.w;
        }
        red[tg * 256 + h] = (p0 + p1) + (p2 + p3);
        __syncthreads();
        if (tg == 0) {
            float v = xp_cur + red[h] + red[256 + h] + red[512 + h] + red[768 + h];
            // tanh(v) = 1 - 2/(exp(2v)+1); exact at +/-inf.
            float e2 = __expf(2.f * v);
            hstate[h] = 1.f - 2.f / (e2 + 1.f);
        }
        __syncthreads();
        xp_cur = xp_next;
    }

    // ---- log_softmax over hstate[0..255] -> out[b, :] ----
    red[tid] = (tid < H_SZ) ? hstate[tid] : -INFINITY;
    __syncthreads();
#pragma unroll
    for (int off = 512; off > 0; off >>= 1) {
        if (tid < off) red[tid] = fmaxf(red[tid], red[tid + off]);
        __syncthreads();
    }
    float m = red[0];
    __syncthreads();
    red[tid] = (tid < H_SZ) ? __expf(hstate[tid] - m) : 0.f;
    __syncthreads();
#pragma unroll
    for (int off = 512; off > 0; off >>= 1) {
        if (tid < off) red[tid] += red[tid + off];
        __syncthreads();
    }
    float lse = m + logf(red[0]);
    if (tid < H_SZ) out[(size_t)b * H_SZ + tid] = hstate[tid] - lse;
}

// ---------------------------------------------------------------------------
extern "C" void kernel_launch(void* const* d_in, const int* in_sizes, int n_in,
                              void* d_out, int out_size, void* d_ws, size_t ws_size,
                              hipStream_t stream) {
    const int*   X    = (const int*)  d_in[0];
    const float* emb  = (const float*)d_in[1];
    const float* W_ih = (const float*)d_in[2];
    const float* W_hh = (const float*)d_in[3];
    const float* b_ih = (const float*)d_in[4];
    const float* b_hh = (const float*)d_in[5];
    float* out   = (float*)d_out;
    float* xproj = (float*)d_ws;   // S*B*H fp32 = 134.2 MB of workspace

    dim3 g1((S_LEN * B_SZ) / ROWS_PER_BLOCK);   // 1024 blocks
    embed_proj_kernel<<<g1, 256, 0, stream>>>(X, emb, W_ih, b_ih, b_hh, xproj);

    rnn_scan_kernel<<<dim3(B_SZ), 1024, 0, stream>>>(xproj, W_hh, out);
}

// Round 2
// 709.276 us; speedup vs baseline: 2.2866x; 2.2866x over previous
//
#include <hip/hip_runtime.h>
#include <math.h>

// Problem constants: S=512, B=256, V=100000, E=128, H=256
#define S_LEN 512
#define B_SZ  256
#define E_SZ  128
#define H_SZ  256

typedef __attribute__((ext_vector_type(8))) short bf16x8;
typedef __attribute__((ext_vector_type(4))) short bf16x4;
typedef __attribute__((ext_vector_type(4))) float f32x4;

__device__ __forceinline__ short f2bf(float f) {
    union { float f; unsigned u; } v; v.f = f;
    unsigned r = v.u + 0x7FFFu + ((v.u >> 16) & 1u);   // RNE
    return (short)(r >> 16);
}

// ---------------------------------------------------------------------------
// Kernel 1: embedding gather + input projection, fp32 LDS-tiled GEMM.
// Tile: 64 rows x 256 h, K=128 staged in 4 phases of 32. 256 threads,
// per-thread 8 rows x 8 h register tile (64 accs).
// ---------------------------------------------------------------------------
#define K1_ROWS 64
#define K1_KP   32
#define K1_AP   (K1_ROWS + 4)   // pad to spread banks
#define K1_WP   (H_SZ + 4)

__global__ __launch_bounds__(256) void embed_proj_kernel(
    const int*   __restrict__ X,
    const float* __restrict__ emb,
    const float* __restrict__ W_ih,
    const float* __restrict__ b_ih,
    const float* __restrict__ b_hh,
    float*       __restrict__ xproj)
{
    __shared__ int   toks[K1_ROWS];
    __shared__ float A_lds[K1_KP][K1_AP];   // [k][row]
    __shared__ float W_lds[K1_KP][K1_WP];   // [k][h]

    const int tid  = threadIdx.x;
    const int row0 = blockIdx.x * K1_ROWS;

    if (tid < K1_ROWS) toks[tid] = X[row0 + tid];

    const int r0 = (tid & 7) * 8;          // 8 rows
    const int h0 = (tid >> 3) * 8;         // 8 h   (tid>>3 in 0..31)

    float acc[8][8];
#pragma unroll
    for (int i = 0; i < 8; ++i)
#pragma unroll
        for (int j = 0; j < 8; ++j) acc[i][j] = 0.f;

    __syncthreads();

    const int ar = tid >> 2;               // row for A staging
    const int ak = (tid & 3) * 8;          // k-chunk for A staging

#pragma unroll
    for (int p = 0; p < E_SZ / K1_KP; ++p) {
        // ---- stage A tile (gathered embedding rows), transposed [k][row] ----
        {
            const float4* src = (const float4*)(emb + (size_t)toks[ar] * E_SZ + p * K1_KP + ak);
            float4 v0 = src[0], v1 = src[1];
            A_lds[ak+0][ar] = v0.x; A_lds[ak+1][ar] = v0.y;
            A_lds[ak+2][ar] = v0.z; A_lds[ak+3][ar] = v0.w;
            A_lds[ak+4][ar] = v1.x; A_lds[ak+5][ar] = v1.y;
            A_lds[ak+6][ar] = v1.z; A_lds[ak+7][ar] = v1.w;
        }
        // ---- stage W tile, transposed [k][h]: thread tid = h ----
        {
            const float4* src = (const float4*)(W_ih + (size_t)tid * E_SZ + p * K1_KP);
#pragma unroll
            for (int j = 0; j < 8; ++j) {
                float4 v = src[j];
                W_lds[j*4+0][tid] = v.x; W_lds[j*4+1][tid] = v.y;
                W_lds[j*4+2][tid] = v.z; W_lds[j*4+3][tid] = v.w;
            }
        }
        __syncthreads();

#pragma unroll 4
        for (int k = 0; k < K1_KP; ++k) {
            const float4 a0 = *(const float4*)&A_lds[k][r0];
            const float4 a1 = *(const float4*)&A_lds[k][r0 + 4];
            const float4 w0 = *(const float4*)&W_lds[k][h0];
            const float4 w1 = *(const float4*)&W_lds[k][h0 + 4];
            const float av[8] = {a0.x,a0.y,a0.z,a0.w,a1.x,a1.y,a1.z,a1.w};
            const float wv[8] = {w0.x,w0.y,w0.z,w0.w,w1.x,w1.y,w1.z,w1.w};
#pragma unroll
            for (int i = 0; i < 8; ++i)
#pragma unroll
                for (int j = 0; j < 8; ++j)
                    acc[i][j] += av[i] * wv[j];
        }
        __syncthreads();
    }

    // ---- epilogue: add bias, store 8 rows x 8 h ----
    float bias[8];
#pragma unroll
    for (int j = 0; j < 8; ++j) bias[j] = b_ih[h0 + j] + b_hh[h0 + j];

#pragma unroll
    for (int i = 0; i < 8; ++i) {
        const size_t row = (size_t)(row0 + r0 + i);
        float4 o0, o1;
        o0.x = acc[i][0] + bias[0]; o0.y = acc[i][1] + bias[1];
        o0.z = acc[i][2] + bias[2]; o0.w = acc[i][3] + bias[3];
        o1.x = acc[i][4] + bias[4]; o1.y = acc[i][5] + bias[5];
        o1.z = acc[i][6] + bias[6]; o1.w = acc[i][7] + bias[7];
        *(float4*)&xproj[row * H_SZ + h0]     = o0;
        *(float4*)&xproj[row * H_SZ + h0 + 4] = o1;
    }
}

// ---------------------------------------------------------------------------
// Kernel 2: MFMA recurrent scan + log_softmax.
// 16 blocks x 16 batch rows. 256 threads = 4 waves; wave owns 4 m-tiles
// (64 h_out). Formulation: D[m=h_out][n=batch] = W_hh * H^T so that
//   - A-operand = W_hh fragments, constant, held in 128 VGPRs/wave
//   - B-operand = state, read as 8 x ds_read_b128 per wave per step
//   - D (col=lane&15 -> batch, row=quad*4+reg -> h) writes back as
//     contiguous bf16x4 -> exactly next step's B-fragment layout.
// ---------------------------------------------------------------------------
#define HPAD 264   // 256 + 8 bf16 pad: keeps 16B alignment, spreads banks

__global__ __launch_bounds__(256) void rnn_scan_kernel(
    const float* __restrict__ xproj,
    const float* __restrict__ W_hh,
    float*       __restrict__ out)
{
    const int tid  = threadIdx.x;
    const int wave = tid >> 6;
    const int lane = tid & 63;
    const int bl   = lane & 15;     // batch within block
    const int quad = lane >> 4;     // 0..3
    const int B0   = blockIdx.x * 16;

    __shared__ short Hbuf[2][16][HPAD];
    __shared__ float sred[4][16];

    // ---- load W_hh fragments (A-operand, constant through the scan) ----
    // lane holds A[m = (wave*4+mt)*16 + bl][k = kk*32 + quad*8 + j]
    bf16x8 wfrag[4][8];
#pragma unroll
    for (int mt = 0; mt < 4; ++mt) {
        const int h = (wave * 4 + mt) * 16 + bl;
#pragma unroll
        for (int kk = 0; kk < 8; ++kk) {
            const float* wp = W_hh + (size_t)h * H_SZ + kk * 32 + quad * 8;
            float4 x0 = *(const float4*)wp;
            float4 x1 = *(const float4*)(wp + 4);
            bf16x8 f;
            f[0] = f2bf(x0.x); f[1] = f2bf(x0.y); f[2] = f2bf(x0.z); f[3] = f2bf(x0.w);
            f[4] = f2bf(x1.x); f[5] = f2bf(x1.y); f[6] = f2bf(x1.z); f[7] = f2bf(x1.w);
            wfrag[mt][kk] = f;
        }
    }

    // zero initial state
    for (int i = tid; i < 16 * HPAD; i += 256) (&Hbuf[0][0][0])[i] = 0;

    // xp for step 0 (lane's batch row bl; 4 consecutive h per m-tile)
    const float* xpb = xproj + (size_t)(B0 + bl) * H_SZ;
    float4 xq[4];
#pragma unroll
    for (int mt = 0; mt < 4; ++mt)
        xq[mt] = *(const float4*)(xpb + (wave * 4 + mt) * 16 + quad * 4);

    float vf[4][4];   // final-step tanh values (fp32) for softmax
#pragma unroll
    for (int mt = 0; mt < 4; ++mt)
#pragma unroll
        for (int r = 0; r < 4; ++r) vf[mt][r] = 0.f;

    __syncthreads();

    for (int s = 0; s < S_LEN; ++s) {
        const int cur = s & 1, nxt = cur ^ 1;

        // B-fragments: state, k-contiguous per lane
        bf16x8 bfrag[8];
#pragma unroll
        for (int kk = 0; kk < 8; ++kk)
            bfrag[kk] = *(const bf16x8*)&Hbuf[cur][bl][kk * 32 + quad * 8];

        // prefetch next step's xp while MFMAs run
        float4 xq_n[4];
        if (s + 1 < S_LEN) {
            const float* xpn = xpb + (size_t)(s + 1) * B_SZ * H_SZ;
#pragma unroll
            for (int mt = 0; mt < 4; ++mt)
                xq_n[mt] = *(const float4*)(xpn + (wave * 4 + mt) * 16 + quad * 4);
        }

        // D = W_hh * H^T
        f32x4 acc[4];
#pragma unroll
        for (int mt = 0; mt < 4; ++mt) {
            f32x4 a = {0.f, 0.f, 0.f, 0.f};
#pragma unroll
            for (int kk = 0; kk < 8; ++kk)
                a = __builtin_amdgcn_mfma_f32_16x16x32_bf16(wfrag[mt][kk], bfrag[kk], a, 0, 0, 0);
            acc[mt] = a;
        }

        // epilogue: v = D + xp, tanh, write back as next state (bf16)
#pragma unroll
        for (int mt = 0; mt < 4; ++mt) {
            const float4 xv = xq[mt];
            float v0 = acc[mt][0] + xv.x;
            float v1 = acc[mt][1] + xv.y;
            float v2 = acc[mt][2] + xv.z;
            float v3 = acc[mt][3] + xv.w;
            // tanh(v) = 1 - 2/(exp(2v)+1), exact at +/-inf
            float t0 = 1.f - 2.f / (__expf(2.f * v0) + 1.f);
            float t1 = 1.f - 2.f / (__expf(2.f * v1) + 1.f);
            float t2 = 1.f - 2.f / (__expf(2.f * v2) + 1.f);
            float t3 = 1.f - 2.f / (__expf(2.f * v3) + 1.f);
            if (s == S_LEN - 1) {
                vf[mt][0] = t0; vf[mt][1] = t1; vf[mt][2] = t2; vf[mt][3] = t3;
            }
            bf16x4 pk;
            pk[0] = f2bf(t0); pk[1] = f2bf(t1); pk[2] = f2bf(t2); pk[3] = f2bf(t3);
            *(bf16x4*)&Hbuf[nxt][bl][(wave * 4 + mt) * 16 + quad * 4] = pk;
        }
#pragma unroll
        for (int mt = 0; mt < 4; ++mt) xq[mt] = xq_n[mt];
        __syncthreads();
    }

    // ---- log_softmax over h for each batch row (lane's row = bl) ----
    float m = -1e30f;
#pragma unroll
    for (int mt = 0; mt < 4; ++mt)
#pragma unroll
        for (int r = 0; r < 4; ++r) m = fmaxf(m, vf[mt][r]);
    m = fmaxf(m, __shfl_xor(m, 16));
    m = fmaxf(m, __shfl_xor(m, 32));
    if (lane < 16) sred[wave][bl] = m;
    __syncthreads();
    m = fmaxf(fmaxf(sred[0][bl], sred[1][bl]), fmaxf(sred[2][bl], sred[3][bl]));
    __syncthreads();

    float ss = 0.f;
#pragma unroll
    for (int mt = 0; mt < 4; ++mt)
#pragma unroll
        for (int r = 0; r < 4; ++r) ss += __expf(vf[mt][r] - m);
    ss += __shfl_xor(ss, 16);
    ss += __shfl_xor(ss, 32);
    if (lane < 16) sred[wave][bl] = ss;
    __syncthreads();
    const float tot = sred[0][bl] + sred[1][bl] + sred[2][bl] + sred[3][bl];
    const float lse = m + __logf(tot);

#pragma unroll
    for (int mt = 0; mt < 4; ++mt) {
        float4 o;
        o.x = vf[mt][0] - lse; o.y = vf[mt][1] - lse;
        o.z = vf[mt][2] - lse; o.w = vf[mt][3] - lse;
        *(float4*)&out[(size_t)(B0 + bl) * H_SZ + (wave * 4 + mt) * 16 + quad * 4] = o;
    }
}

// ---------------------------------------------------------------------------
extern "C" void kernel_launch(void* const* d_in, const int* in_sizes, int n_in,
                              void* d_out, int out_size, void* d_ws, size_t ws_size,
                              hipStream_t stream) {
    const int*   X    = (const int*)  d_in[0];
    const float* emb  = (const float*)d_in[1];
    const float* W_ih = (const float*)d_in[2];
    const float* W_hh = (const float*)d_in[3];
    const float* b_ih = (const float*)d_in[4];
    const float* b_hh = (const float*)d_in[5];
    float* out   = (float*)d_out;
    float* xproj = (float*)d_ws;   // S*B*H fp32 = 134.2 MB

    embed_proj_kernel<<<dim3((S_LEN * B_SZ) / K1_ROWS), 256, 0, stream>>>(
        X, emb, W_ih, b_ih, b_hh, xproj);

    rnn_scan_kernel<<<dim3(B_SZ / 16), 256, 0, stream>>>(xproj, W_hh, out);
}